// Round 6
// baseline (1002.116 us; speedup 1.0000x reference)
//
#include <hip/hip_runtime.h>
#include <hip/hip_bf16.h>

#define N_NODES 100000
#define NPAD    100096          // 782 * 128
#define NRB     782
#define E_EDGES 1600000
#define NBLK_SCAN 98

// histogram-degree params
#define HNR  4                  // node ranges of 32768
#define HP   64                 // edge chunks
#define HCHK 25000              // E / HP
#define HRSZ 32768

#define AS1 __attribute__((address_space(1)))
#define AS3 __attribute__((address_space(3)))

typedef unsigned int   uint;
typedef unsigned short ushort;
typedef __attribute__((ext_vector_type(8))) short bfx8;   // 8 bf16 (4 VGPRs)
typedef __attribute__((ext_vector_type(4))) float fx4;

__device__ __forceinline__ float bf2f(ushort u) {
    return __uint_as_float(((uint)u) << 16);
}
__device__ __forceinline__ ushort f2bf(float f) {
    uint x = __float_as_uint(f);
    return (ushort)((x + 0x7FFFu + ((x >> 16) & 1u)) >> 16);   // RNE
}
// tanh-GELU; |diff vs erf-GELU| <= ~3e-3
__device__ __forceinline__ float gelu_fast(float x) {
    float u = 1.5957691f * __builtin_fmaf(0.044715f * x * x, x, x);
    return x / (1.0f + __expf(-u));
}
__device__ __forceinline__ float wave_sum(float v) {
    #pragma unroll
    for (int m = 1; m < 64; m <<= 1) v += __shfl_xor(v, m, 64);
    return v;
}
// bijective XCD swizzle (m204)
__device__ __forceinline__ int xcd_swz(int orig, int nwg) {
    int q = nwg >> 3, r = nwg & 7;
    int x = orig & 7, o = orig >> 3;
    return (x < r ? x * (q + 1) : r * (q + 1) + (x - r) * q) + o;
}

// ---------------- degree via LDS histograms (no fabric atomics) ----------------
// part[(r*HP + c)][HRSZ/2] u32 words, each = two u16 counts (nodes 2i, 2i+1 of range r)
__global__ void k_hist(const int* __restrict__ idx, uint* __restrict__ part)
{
    __shared__ uint h[HRSZ / 2];
    int c = blockIdx.x & (HP - 1);
    int r = blockIdx.x / HP;
    int t = threadIdx.x;
    for (int i = t; i < HRSZ / 2; i += 256) h[i] = 0u;
    __syncthreads();
    int base = r << 15;
    int e0 = c * HCHK;
    for (int e = e0 + t; e < e0 + HCHK; e += 256) {
        int v = idx[e] - base;
        if ((uint)v < (uint)HRSZ)
            atomicAdd(&h[v >> 1], 1u << ((v & 1) * 16));
    }
    __syncthreads();
    uint* dst = part + ((size_t)blockIdx.x << 14);
    for (int i = t; i < HRSZ / 2; i += 256) dst[i] = h[i];
}

__global__ void k_degmerge(const uint* __restrict__ partO, const uint* __restrict__ partI,
                           int* __restrict__ inc, float* __restrict__ oscale,
                           float* __restrict__ ininv)
{
    int n = blockIdx.x * 256 + threadIdx.x;
    if (n >= NPAD) return;
    int r = n >> 15, i = (n & 32767) >> 1, hi = (n & 1) * 16;
    const uint* po = partO + ((size_t)(r * HP) << 14) + i;
    const uint* pi = partI + ((size_t)(r * HP) << 14) + i;
    uint so = 0, si = 0;
    for (int c = 0; c < HP; ++c) {
        so += (po[(size_t)c << 14] >> hi) & 0xffffu;
        si += (pi[(size_t)c << 14] >> hi) & 0xffffu;
    }
    inc[n] = (int)si;
    oscale[n] = rsqrtf((float)max((int)so, 1));
    ininv[n] = rsqrtf((float)max((int)si, 1));
}

// ---------------- CSR scan + fill ----------------
__global__ void k_scan1(const int* __restrict__ inc, int* __restrict__ coff, int* __restrict__ btot)
{
    __shared__ int a[1024], bsh[1024];
    int t = threadIdx.x;
    int i = blockIdx.x * 1024 + t;
    a[t] = (i < N_NODES) ? inc[i] : 0;
    __syncthreads();
    int* s = a; int* d = bsh;
    for (int dd = 1; dd < 1024; dd <<= 1) {
        int v = s[t] + ((t >= dd) ? s[t - dd] : 0);
        d[t] = v;
        __syncthreads();
        int* tmp = s; s = d; d = tmp;
    }
    if (i < N_NODES) coff[i + 1] = s[t];
    if (t == 1023) btot[blockIdx.x] = s[t];
}

__global__ void k_scan2(int* __restrict__ btot)
{
    __shared__ int a[128], bsh[128];
    int t = threadIdx.x;
    a[t] = (t < NBLK_SCAN) ? btot[t] : 0;
    __syncthreads();
    int* s = a; int* d = bsh;
    for (int dd = 1; dd < 128; dd <<= 1) {
        int v = s[t] + ((t >= dd) ? s[t - dd] : 0);
        d[t] = v;
        __syncthreads();
        int* tmp = s; s = d; d = tmp;
    }
    if (t < NBLK_SCAN) btot[t] = s[t];
}

__global__ void k_scan3(int* __restrict__ coff, const int* __restrict__ btot)
{
    int i = blockIdx.x * 256 + threadIdx.x;
    if (i == 0) coff[0] = 0;
    if (i < N_NODES) {
        int blk = i >> 10;
        if (blk > 0) coff[i + 1] += btot[blk - 1];
    }
}

__global__ void k_fill(const int* __restrict__ src, const int* __restrict__ dst,
                       const int* __restrict__ coff, int* __restrict__ cur, int* __restrict__ eidx)
{
    int e = blockIdx.x * 256 + threadIdx.x;
    if (e < E_EDGES) {
        int d = dst[e];
        int p = coff[d] + atomicAdd(&cur[d], 1);
        eidx[p] = src[e];
    }
}

// xh[r,:] = bf16(x[r,:] * oscale[r])
__global__ void k_xhat(const float* __restrict__ x, const float* __restrict__ oscale,
                       ushort* __restrict__ xh)
{
    size_t i = (size_t)blockIdx.x * 256 + threadIdx.x;
    size_t e0 = i * 4;
    int row = (int)(e0 >> 7);
    uint2 o;
    if (row < N_NODES) {
        float4 v = *(const float4*)(x + e0);
        float s = oscale[row];
        o.x = (uint)f2bf(v.x * s) | ((uint)f2bf(v.y * s) << 16);
        o.y = (uint)f2bf(v.z * s) | ((uint)f2bf(v.w * s) << 16);
    } else {
        o.x = 0u; o.y = 0u;
    }
    *(uint2*)(xh + e0) = o;
}

// one wave per dst row, 4 edges in flight, 16B/lane gather
__global__ void k_agg(const int* __restrict__ off, const int* __restrict__ eidx,
                      const ushort* __restrict__ xh, ushort* __restrict__ agg)
{
    int wid = threadIdx.x >> 6, lane = threadIdx.x & 63;
    int r = blockIdx.x * 4 + wid;
    if (r >= NPAD) return;
    int f = lane & 15;
    int g = lane >> 4;
    float a[8] = {0.f, 0.f, 0.f, 0.f, 0.f, 0.f, 0.f, 0.f};
    if (r < N_NODES) {
        int s = off[r], e = off[r + 1];
        for (int i = s + g; i < e; i += 4) {
            int sv = eidx[i];
            bfx8 v = *(const bfx8*)(xh + (size_t)sv * 128 + f * 8);
            #pragma unroll
            for (int k = 0; k < 8; ++k) a[k] += bf2f((ushort)v[k]);
        }
    }
    #pragma unroll
    for (int k = 0; k < 8; ++k) {
        a[k] += __shfl_xor(a[k], 16, 64);
        a[k] += __shfl_xor(a[k], 32, 64);
    }
    if (g == 0) {
        bfx8 o;
        #pragma unroll
        for (int k = 0; k < 8; ++k) o[k] = (short)f2bf(a[k]);
        *(bfx8*)(agg + (size_t)r * 128 + f * 8) = o;
    }
}

// transpose+convert weight [K,M] f32 -> [M,K] bf16
__global__ void k_wT(const float* __restrict__ W, int K, int M, ushort* __restrict__ Wt)
{
    int id = blockIdx.x * 256 + threadIdx.x;
    if (id < K * M) {
        int m = id / K, k = id - m * K;
        Wt[id] = f2bf(W[(size_t)k * M + m]);
    }
}

// ff2 weight prep with LN-gamma fold: Wt[m*512+k]=bf16(g[k]*W[k,m]);
// u[m]=sum_k g W; t[m]=sum_k b W + b2[m]
__global__ void k_wT_ln(const float* __restrict__ W, const float* __restrict__ g,
                        const float* __restrict__ b, const float* __restrict__ b2,
                        ushort* __restrict__ Wt, float* __restrict__ u, float* __restrict__ t)
{
    int wid = threadIdx.x >> 6, lane = threadIdx.x & 63;
    int m = blockIdx.x * 4 + wid;
    if (m >= 128) return;
    float us = 0.f, ts = 0.f;
    for (int k = lane; k < 512; k += 64) {
        float w = W[(size_t)k * 128 + m];
        float gk = g[k], bk = b[k];
        Wt[(size_t)m * 512 + k] = f2bf(gk * w);
        us += gk * w; ts += bk * w;
    }
    us = wave_sum(us); ts = wave_sum(ts);
    if (lane == 0) { u[m] = us; t[m] = ts + b2[m]; }
}

// ---------------- GEMM: C = A @ Bt^T, bf16 MFMA ----------------
// EPI: 0 = rowv0[row]*acc + colv0[col]
//      1 = gelu(acc + colv0[col])
//      3 = rowv0[row]*acc + rowv1[row]*colv1[col] + colv0[col]   (folded LN)
// STATS: 0 none, 1 col sum/sumsq partials (per block, non-atomic), 2 row partials
template <int EPI, int STATS>
__global__ __launch_bounds__(256, 4) void k_gemm(
    const ushort* __restrict__ A, const ushort* __restrict__ Bt,
    ushort* __restrict__ C, int K, int M,
    const float* __restrict__ colv0, const float* __restrict__ rowv0,
    const float* __restrict__ rowv1, const float* __restrict__ colv1,
    float* __restrict__ pS, float* __restrict__ pQ, int grb0)
{
    __shared__ __align__(16) char smem[32768 + (STATS == 1 ? 1024 : 0)];
    char* AsB = smem;
    char* BsB = smem + 16384;

    const int nwg = gridDim.x;
    const int wgid = xcd_swz(blockIdx.x, nwg);
    const int nCB = M >> 7;
    const int cb = wgid % nCB;
    const int rb = wgid / nCB;
    const int tid = threadIdx.x;
    const int lane = tid & 63;
    const int wid = tid >> 6;
    const int m0 = (wid >> 1) * 64;
    const int n0 = (wid & 1) * 64;
    const int frl = lane & 15;
    const int kg = lane >> 4;

    float* statsf = (float*)(smem + 32768);
    if (STATS == 1 && tid < 128) { statsf[tid] = 0.f; statsf[128 + tid] = 0.f; }

    fx4 acc[4][4] = {};

    const ushort* Arow0 = A + (size_t)(rb * 128) * K;
    const ushort* Brow0 = Bt + (size_t)(cb * 128) * K;

    for (int kb = 0; kb < K; kb += 64) {
        #pragma unroll
        for (int c = 0; c < 4; ++c) {
            int b = c * 4096 + tid * 16;
            int row = b >> 7;
            int cibs = (b & 127) ^ ((row & 7) << 4);
            const char* ga = (const char*)(Arow0 + (size_t)row * K + kb) + cibs;
            const char* gb = (const char*)(Brow0 + (size_t)row * K + kb) + cibs;
            char* la = AsB + c * 4096 + (wid << 10);
            char* lb = BsB + c * 4096 + (wid << 10);
            __builtin_amdgcn_global_load_lds((const AS1 void*)ga, (AS3 void*)la, 16, 0, 0);
            __builtin_amdgcn_global_load_lds((const AS1 void*)gb, (AS3 void*)lb, 16, 0, 0);
        }
        __syncthreads();
        #pragma unroll
        for (int kk = 0; kk < 2; ++kk) {
            bfx8 av[4], bv[4];
            #pragma unroll
            for (int i = 0; i < 4; ++i) {
                int ar = m0 + i * 16 + frl;
                int ab = (ar * 128 + kk * 64 + kg * 16) ^ ((ar & 7) << 4);
                av[i] = *(const bfx8*)(AsB + ab);
                int br = n0 + i * 16 + frl;
                int bb = (br * 128 + kk * 64 + kg * 16) ^ ((br & 7) << 4);
                bv[i] = *(const bfx8*)(BsB + bb);
            }
            #pragma unroll
            for (int i = 0; i < 4; ++i)
                #pragma unroll
                for (int j = 0; j < 4; ++j)
                    acc[i][j] = __builtin_amdgcn_mfma_f32_16x16x32_bf16(av[i], bv[j], acc[i][j], 0, 0, 0);
        }
        __syncthreads();
    }

    // ---- epilogue: epi (+ col partials) -> LDS C-tile ----
    float sL[4] = {0.f, 0.f, 0.f, 0.f}, qL[4] = {0.f, 0.f, 0.f, 0.f};
    #pragma unroll
    for (int j = 0; j < 4; ++j) {
        int colL = n0 + j * 16 + frl;
        float c0 = colv0[cb * 128 + colL];
        float c1 = (EPI == 3) ? colv1[cb * 128 + colL] : 0.f;
        #pragma unroll
        for (int i = 0; i < 4; ++i) {
            int rbaseL = m0 + i * 16 + kg * 4;
            #pragma unroll
            for (int r = 0; r < 4; ++r) {
                float v = acc[i][j][r];
                int rowL = rbaseL + r;
                int grow = (grb0 + rb) * 128 + rowL;
                if (EPI == 0)      v = v * rowv0[grow] + c0;
                else if (EPI == 1) v = gelu_fast(v + c0);
                else if (EPI == 3) v = rowv0[grow] * v + rowv1[grow] * c1 + c0;
                if (STATS == 1) {
                    if (grow < N_NODES) { sL[j] += v; qL[j] += v * v; }
                }
                int boff = rowL * 256 + ((colL * 2) ^ ((rowL & 7) << 4));
                *(ushort*)(smem + boff) = f2bf(v);
            }
        }
    }
    if (STATS == 1) {
        #pragma unroll
        for (int j = 0; j < 4; ++j) {
            float s = sL[j], q = qL[j];
            s += __shfl_xor(s, 16, 64); s += __shfl_xor(s, 32, 64);
            q += __shfl_xor(q, 16, 64); q += __shfl_xor(q, 32, 64);
            if (kg == 0) {
                atomicAdd(&statsf[n0 + j * 16 + frl], s);
                atomicAdd(&statsf[128 + n0 + j * 16 + frl], q);
            }
        }
    }
    __syncthreads();
    // coalesced global write: 16 lanes x 16B = 256B per row
    {
        int r2 = tid >> 4;
        int s2 = tid & 15;
        #pragma unroll
        for (int pass = 0; pass < 8; ++pass) {
            int rowL = pass * 16 + r2;
            int boff = rowL * 256 + ((s2 * 16) ^ ((rowL & 7) << 4));
            bfx8 v = *(const bfx8*)(smem + boff);
            *(bfx8*)((char*)(C + (size_t)((grb0 + rb) * 128 + rowL - grb0 * 128) * M + cb * 128) + s2 * 16) = v;
        }
    }
    if (STATS == 1 && tid < 128) {
        size_t pidx = ((size_t)(grb0 + rb) * nCB + cb) * 128 + tid;
        pS[pidx] = statsf[tid];
        pQ[pidx] = statsf[128 + tid];
    }
    if (STATS == 2) {
        // row sum/sumsq from bf16 C-tile (one row-half per thread)
        int rowL = tid >> 1, half = tid & 1;
        float s = 0.f, q = 0.f;
        #pragma unroll
        for (int ss = 0; ss < 8; ++ss) {
            int boff = rowL * 256 + (((half * 64 + ss * 8) * 2) ^ ((rowL & 7) << 4));
            bfx8 v = *(const bfx8*)(smem + boff);
            #pragma unroll
            for (int k2 = 0; k2 < 8; ++k2) {
                float f = bf2f((ushort)v[k2]);
                s += f; q += f * f;
            }
        }
        s += __shfl_xor(s, 1, 64);
        q += __shfl_xor(q, 1, 64);
        if (half == 0) {
            size_t pidx = (size_t)cb * NPAD + (size_t)(grb0 + rb) * 128 + rowL;
            pS[pidx] = s;
            pQ[pidx] = q;
        }
    }
}

// LN row stats: s_r = rsqrt(var+eps), c_r = -mean*s_r
__global__ void k_rowmerge(const float* __restrict__ pS, const float* __restrict__ pQ,
                           float* __restrict__ lnS, float* __restrict__ lnC)
{
    int r = blockIdx.x * 256 + threadIdx.x;
    if (r >= NPAD) return;
    float s = 0.f, q = 0.f;
    #pragma unroll
    for (int cb = 0; cb < 4; ++cb) {
        s += pS[(size_t)cb * NPAD + r];
        q += pQ[(size_t)cb * NPAD + r];
    }
    float mean = s * (1.f / 512.f);
    float var = fmaxf(q * (1.f / 512.f) - mean * mean, 0.f);
    float sr = rsqrtf(var + 1e-5f);
    lnS[r] = sr;
    lnC[r] = -mean * sr;
}

// merge col partials -> sums
__global__ void k_colmerge(const float* __restrict__ pS, const float* __restrict__ pQ,
                           float* __restrict__ oS, float* __restrict__ oQ, int M)
{
    int m = blockIdx.x * 256 + threadIdx.x;
    if (m >= M) return;
    int nCB = M >> 7, cb = m >> 7, colL = m & 127;
    float s = 0.f, q = 0.f;
    for (int rb = 0; rb < NRB; ++rb) {
        size_t idx = ((size_t)rb * nCB + cb) * 128 + colL;
        s += pS[idx]; q += pQ[idx];
    }
    oS[m] = s; oQ[m] = q;
}

// fold BN(prev-layer cols) into next weight
__global__ void k_fold(const float* __restrict__ W, const float* __restrict__ bw,
                       const float* __restrict__ g, const float* __restrict__ bb,
                       const float* __restrict__ sum, const float* __restrict__ sqs,
                       int K, int M, ushort* __restrict__ WtO, float* __restrict__ bO)
{
    int wid = threadIdx.x >> 6, lane = threadIdx.x & 63;
    int m = blockIdx.x * 4 + wid;
    if (m >= M) return;
    float acc = 0.f;
    for (int k = lane; k < K; k += 64) {
        float mean = sum[k] * (1.f / (float)N_NODES);
        float var = sqs[k] * (1.f / (float)N_NODES) - mean * mean;
        float s = g[k] * rsqrtf(var + 1e-5f);
        float t = bb[k] - mean * s;
        float w = W[(size_t)k * M + m];
        WtO[(size_t)m * K + k] = f2bf(w * s);
        acc += t * w;
    }
    acc = wave_sum(acc);
    if (lane == 0) bO[m] = bw[m] + acc;
}

// out[r] = dot(m3[r,:128], w4) + b4
__global__ void k_out(const ushort* __restrict__ m3, const ushort* __restrict__ w4,
                      const float* __restrict__ b4, float* __restrict__ out)
{
    int wid = threadIdx.x >> 6, lane = threadIdx.x & 63;
    int r = blockIdx.x * 4 + wid;
    if (r >= N_NODES) return;
    uint u = *(const uint*)(m3 + (size_t)r * 128 + lane * 2);
    uint w = *(const uint*)(w4 + lane * 2);
    float acc = bf2f((ushort)(u & 0xffffu)) * bf2f((ushort)(w & 0xffffu))
              + bf2f((ushort)(u >> 16)) * bf2f((ushort)(w >> 16));
    acc = wave_sum(acc);
    if (lane == 0) out[r] = acc + b4[0];
}

extern "C" void kernel_launch(void* const* d_in, const int* in_sizes, int n_in,
                              void* d_out, int out_size, void* d_ws, size_t ws_size,
                              hipStream_t stream)
{
    const float* x     = (const float*)d_in[0];
    const int*   src   = (const int*)d_in[1];
    const int*   dst   = (const int*)d_in[2];
    const float* gcn_w = (const float*)d_in[3];
    const float* gcn_b = (const float*)d_in[4];
    const float* ff_w1 = (const float*)d_in[5];
    const float* ff_b1 = (const float*)d_in[6];
    const float* ln_g  = (const float*)d_in[7];
    const float* ln_b  = (const float*)d_in[8];
    const float* ff_w2 = (const float*)d_in[9];
    const float* ff_b2 = (const float*)d_in[10];
    const float* fc1_w = (const float*)d_in[11];
    const float* fc1_b = (const float*)d_in[12];
    const float* bn1_g = (const float*)d_in[13];
    const float* bn1_b = (const float*)d_in[14];
    const float* fc2_w = (const float*)d_in[15];
    const float* fc2_b = (const float*)d_in[16];
    const float* bn2_g = (const float*)d_in[17];
    const float* bn2_b = (const float*)d_in[18];
    const float* fc3_w = (const float*)d_in[19];
    const float* fc3_b = (const float*)d_in[20];
    const float* bn3_g = (const float*)d_in[21];
    const float* bn3_b = (const float*)d_in[22];
    const float* fc4_w = (const float*)d_in[23];
    const float* fc4_b = (const float*)d_in[24];
    float* out = (float*)d_out;
    (void)in_sizes; (void)n_in; (void)out_size;

    char* base = (char*)d_ws;
    char* p = base;
    auto alloc = [&](size_t bytes) -> char* {
        char* r = p;
        p += (bytes + 255) & ~(size_t)255;
        return r;
    };
    int*    inc    = (int*)alloc((size_t)NPAD * 4);
    int*    cur    = (int*)alloc((size_t)NPAD * 4);
    int*    coff   = (int*)alloc(((size_t)NPAD + 1) * 4);
    int*    btot   = (int*)alloc(128 * 4);
    int*    eidx   = (int*)alloc((size_t)E_EDGES * 4);
    float*  oscale = (float*)alloc((size_t)NPAD * 4);
    float*  ininv  = (float*)alloc((size_t)NPAD * 4);
    float*  bns    = (float*)alloc(6 * 512 * 4);
    float*  b2p    = (float*)alloc(512 * 4);
    float*  b3p    = (float*)alloc(128 * 4);
    float*  b4p    = (float*)alloc(4);
    float*  lnS    = (float*)alloc((size_t)NPAD * 4);
    float*  lnC    = (float*)alloc((size_t)NPAD * 4);
    float*  lnU    = (float*)alloc(128 * 4);
    float*  lnT    = (float*)alloc(128 * 4);
    float*  pS     = (float*)alloc((size_t)4 * NPAD * 4);   // row/col partials (max 1.6MB)
    float*  pQ     = (float*)alloc((size_t)4 * NPAD * 4);
    ushort* gwT    = (ushort*)alloc(128 * 128 * 2);
    ushort* ff1T   = (ushort*)alloc(512 * 128 * 2);
    ushort* ff2T   = (ushort*)alloc(128 * 512 * 2);
    ushort* fc1T   = (ushort*)alloc(512 * 128 * 2);
    ushort* fc2T   = (ushort*)alloc(512 * 512 * 2);
    ushort* fc3T   = (ushort*)alloc(128 * 512 * 2);
    ushort* w4t    = (ushort*)alloc(128 * 2);
    ushort* buf1   = (ushort*)alloc((size_t)NPAD * 128 * 2);  // h -> h2 -> (fc2 tmp) -> m3
    ushort* bufC   = (ushort*)alloc((size_t)NPAD * 512 * 2);  // hist partials -> xh+agg -> f -> m1 [-> m2]

    size_t used = (size_t)(p - base);
    bool   sep  = (used + (size_t)NPAD * 512 * 2) <= ws_size;
    ushort* m2  = sep ? (ushort*)alloc((size_t)NPAD * 512 * 2) : bufC;

    // transient aliases inside bufC (dead before xh/agg/f usage)
    uint* partO = (uint*)bufC;                                   // 16.78 MB
    uint* partI = partO + (size_t)HNR * HP * (HRSZ / 2);         // 16.78 MB
    ushort* xh  = bufC;
    ushort* agg = bufC + (size_t)NPAD * 128;

    float* bn1s = bns;
    float* bn1q = bns + 512;
    float* bn2s = bns + 1024;
    float* bn2q = bns + 1536;
    float* bn3s = bns + 2048;
    float* bn3q = bns + 2560;

    hipMemsetAsync(cur, 0, (size_t)NPAD * 4, stream);

    // degrees via LDS histograms
    k_hist<<<HNR * HP, 256, 0, stream>>>(src, partO);
    k_hist<<<HNR * HP, 256, 0, stream>>>(dst, partI);
    k_degmerge<<<(NPAD + 255) / 256, 256, 0, stream>>>(partO, partI, inc, oscale, ininv);
    k_scan1<<<NBLK_SCAN, 1024, 0, stream>>>(inc, coff, btot);
    k_scan2<<<1, 128, 0, stream>>>(btot);
    k_scan3<<<(N_NODES + 255) / 256, 256, 0, stream>>>(coff, btot);
    k_fill<<<E_EDGES / 256, 256, 0, stream>>>(src, dst, coff, cur, eidx);
    k_xhat<<<(NPAD / 256) * 32, 256, 0, stream>>>(x, oscale, xh);
    k_agg<<<NPAD / 4, 256, 0, stream>>>(coff, eidx, xh, agg);

    k_wT<<<(128 * 128) / 256, 256, 0, stream>>>(gcn_w, 128, 128, gwT);
    k_wT<<<(128 * 512) / 256, 256, 0, stream>>>(ff_w1, 128, 512, ff1T);
    k_wT<<<(128 * 512) / 256, 256, 0, stream>>>(fc1_w, 128, 512, fc1T);
    k_wT_ln<<<32, 256, 0, stream>>>(ff_w2, ln_g, ln_b, ff_b2, ff2T, lnU, lnT);

    // GCN: h = (agg @ gcn_w) * ininv + gcn_b
    k_gemm<0, 0><<<NRB, 256, 0, stream>>>(agg, gwT, buf1, 128, 128,
                                          gcn_b, ininv, nullptr, nullptr, nullptr, nullptr, 0);
    // f = gelu(h @ ff_w1 + ff_b1) + row partials for LN
    k_gemm<1, 2><<<4 * NRB, 256, 0, stream>>>(buf1, ff1T, bufC, 128, 512,
                                              ff_b1, nullptr, nullptr, nullptr, pS, pQ, 0);
    k_rowmerge<<<(NPAD + 255) / 256, 256, 0, stream>>>(pS, pQ, lnS, lnC);
    // h2 = LN(f) @ ff_w2 + ff_b2 folded: s_r*acc + c_r*u + t
    k_gemm<3, 0><<<NRB, 256, 0, stream>>>(bufC, ff2T, buf1, 512, 128,
                                          lnT, lnS, lnC, lnU, nullptr, nullptr, 0);
    // m1 = gelu(h2 @ fc1_w + fc1_b) + bn1 col partials
    k_gemm<1, 1><<<4 * NRB, 256, 0, stream>>>(buf1, fc1T, bufC, 128, 512,
                                              fc1_b, nullptr, nullptr, nullptr, pS, pQ, 0);
    k_colmerge<<<2, 256, 0, stream>>>(pS, pQ, bn1s, bn1q, 512);
    k_fold<<<512 / 4, 256, 0, stream>>>(fc2_w, fc2_b, bn1_g, bn1_b, bn1s, bn1q, 512, 512, fc2T, b2p);
    // m2 = gelu(bn1(m1) @ fc2_w + fc2_b) + bn2 col partials
    if (sep) {
        k_gemm<1, 1><<<4 * NRB, 256, 0, stream>>>(bufC, fc2T, m2, 512, 512,
                                                  b2p, nullptr, nullptr, nullptr, pS, pQ, 0);
    } else {
        const int cOff[6] = {0, 195, 390, 585, 780, 782};
        for (int c = 0; c < 5; ++c) {
            int rb0 = cOff[c], nrb = cOff[c + 1] - rb0;
            k_gemm<1, 1><<<nrb * 4, 256, 0, stream>>>(bufC + (size_t)rb0 * 128 * 512, fc2T,
                                                      buf1, 512, 512,
                                                      b2p, nullptr, nullptr, nullptr, pS, pQ, rb0);
            hipMemcpyAsync(bufC + (size_t)rb0 * 128 * 512, buf1,
                           (size_t)nrb * 128 * 512 * 2, hipMemcpyDeviceToDevice, stream);
        }
    }
    k_colmerge<<<2, 256, 0, stream>>>(pS, pQ, bn2s, bn2q, 512);
    k_fold<<<128 / 4, 256, 0, stream>>>(fc3_w, fc3_b, bn2_g, bn2_b, bn2s, bn2q, 512, 128, fc3T, b3p);
    // m3 = gelu(bn2(m2) @ fc3_w + fc3_b) + bn3 col partials
    k_gemm<1, 1><<<NRB, 256, 0, stream>>>(m2, fc3T, buf1, 512, 128,
                                          b3p, nullptr, nullptr, nullptr, pS, pQ, 0);
    k_colmerge<<<1, 256, 0, stream>>>(pS, pQ, bn3s, bn3q, 128);
    k_fold<<<1, 256, 0, stream>>>(fc4_w, fc4_b, bn3_g, bn3_b, bn3s, bn3q, 128, 1, w4t, b4p);
    k_out<<<N_NODES / 4, 256, 0, stream>>>(buf1, w4t, b4p, out);
}

// Round 7
// 670.684 us; speedup vs baseline: 1.4942x; 1.4942x over previous
//
#include <hip/hip_runtime.h>
#include <hip/hip_bf16.h>

#define N_NODES 100000
#define NPAD    100096          // 782 * 128
#define NRB     782
#define E_EDGES 1600000
#define NBLK_SCAN 98

// histogram-degree params
#define HNR  4                  // node ranges of 32768
#define HP   64                 // edge chunks
#define HCHK 25000              // E / HP
#define HRSZ 32768

#define AS1 __attribute__((address_space(1)))
#define AS3 __attribute__((address_space(3)))

typedef unsigned int   uint;
typedef unsigned short ushort;
typedef __attribute__((ext_vector_type(8))) short bfx8;   // 8 bf16 (4 VGPRs)
typedef __attribute__((ext_vector_type(4))) float fx4;

__device__ __forceinline__ float bf2f(ushort u) {
    return __uint_as_float(((uint)u) << 16);
}
__device__ __forceinline__ ushort f2bf(float f) {
    uint x = __float_as_uint(f);
    return (ushort)((x + 0x7FFFu + ((x >> 16) & 1u)) >> 16);   // RNE
}
// tanh-GELU; |diff vs erf-GELU| <= ~3e-3
__device__ __forceinline__ float gelu_fast(float x) {
    float u = 1.5957691f * __builtin_fmaf(0.044715f * x * x, x, x);
    return x / (1.0f + __expf(-u));
}
__device__ __forceinline__ float wave_sum(float v) {
    #pragma unroll
    for (int m = 1; m < 64; m <<= 1) v += __shfl_xor(v, m, 64);
    return v;
}
// bijective XCD swizzle (m204)
__device__ __forceinline__ int xcd_swz(int orig, int nwg) {
    int q = nwg >> 3, r = nwg & 7;
    int x = orig & 7, o = orig >> 3;
    return (x < r ? x * (q + 1) : r * (q + 1) + (x - r) * q) + o;
}

// ---------------- degree via LDS histograms (no fabric atomics) ----------------
__global__ void k_hist(const int* __restrict__ idx, uint* __restrict__ part)
{
    __shared__ uint h[HRSZ / 2];
    int c = blockIdx.x & (HP - 1);
    int r = blockIdx.x / HP;
    int t = threadIdx.x;
    for (int i = t; i < HRSZ / 2; i += 256) h[i] = 0u;
    __syncthreads();
    int base = r << 15;
    int e0 = c * HCHK;
    for (int e = e0 + t; e < e0 + HCHK; e += 256) {
        int v = idx[e] - base;
        if ((uint)v < (uint)HRSZ)
            atomicAdd(&h[v >> 1], 1u << ((v & 1) * 16));
    }
    __syncthreads();
    uint* dst = part + ((size_t)blockIdx.x << 14);
    for (int i = t; i < HRSZ / 2; i += 256) dst[i] = h[i];
}

__global__ void k_degmerge(const uint* __restrict__ partO, const uint* __restrict__ partI,
                           int* __restrict__ inc, float* __restrict__ oscale,
                           float* __restrict__ ininv)
{
    int n = blockIdx.x * 256 + threadIdx.x;
    if (n >= NPAD) return;
    int r = n >> 15, i = (n & 32767) >> 1, hi = (n & 1) * 16;
    const uint* po = partO + ((size_t)(r * HP) << 14) + i;
    const uint* pi = partI + ((size_t)(r * HP) << 14) + i;
    uint so = 0, si = 0;
    for (int c = 0; c < HP; ++c) {
        so += (po[(size_t)c << 14] >> hi) & 0xffffu;
        si += (pi[(size_t)c << 14] >> hi) & 0xffffu;
    }
    inc[n] = (int)si;
    oscale[n] = rsqrtf((float)max((int)so, 1));
    ininv[n] = rsqrtf((float)max((int)si, 1));
}

// ---------------- CSR scan + fill ----------------
__global__ void k_scan1(const int* __restrict__ inc, int* __restrict__ coff, int* __restrict__ btot)
{
    __shared__ int a[1024], bsh[1024];
    int t = threadIdx.x;
    int i = blockIdx.x * 1024 + t;
    a[t] = (i < N_NODES) ? inc[i] : 0;
    __syncthreads();
    int* s = a; int* d = bsh;
    for (int dd = 1; dd < 1024; dd <<= 1) {
        int v = s[t] + ((t >= dd) ? s[t - dd] : 0);
        d[t] = v;
        __syncthreads();
        int* tmp = s; s = d; d = tmp;
    }
    if (i < N_NODES) coff[i + 1] = s[t];
    if (t == 1023) btot[blockIdx.x] = s[t];
}

__global__ void k_scan2(int* __restrict__ btot)
{
    __shared__ int a[128], bsh[128];
    int t = threadIdx.x;
    a[t] = (t < NBLK_SCAN) ? btot[t] : 0;
    __syncthreads();
    int* s = a; int* d = bsh;
    for (int dd = 1; dd < 128; dd <<= 1) {
        int v = s[t] + ((t >= dd) ? s[t - dd] : 0);
        d[t] = v;
        __syncthreads();
        int* tmp = s; s = d; d = tmp;
    }
    if (t < NBLK_SCAN) btot[t] = s[t];
}

__global__ void k_scan3(int* __restrict__ coff, const int* __restrict__ btot)
{
    int i = blockIdx.x * 256 + threadIdx.x;
    if (i == 0) coff[0] = 0;
    if (i < N_NODES) {
        int blk = i >> 10;
        if (blk > 0) coff[i + 1] += btot[blk - 1];
    }
}

__global__ void k_fill(const int* __restrict__ src, const int* __restrict__ dst,
                       const int* __restrict__ coff, int* __restrict__ cur, int* __restrict__ eidx)
{
    int e = blockIdx.x * 256 + threadIdx.x;
    if (e < E_EDGES) {
        int d = dst[e];
        int p = coff[d] + atomicAdd(&cur[d], 1);
        eidx[p] = src[e];
    }
}

// xh[r,:] = bf16(x[r,:] * oscale[r])
__global__ void k_xhat(const float* __restrict__ x, const float* __restrict__ oscale,
                       ushort* __restrict__ xh)
{
    size_t i = (size_t)blockIdx.x * 256 + threadIdx.x;
    size_t e0 = i * 4;
    int row = (int)(e0 >> 7);
    uint2 o;
    if (row < N_NODES) {
        float4 v = *(const float4*)(x + e0);
        float s = oscale[row];
        o.x = (uint)f2bf(v.x * s) | ((uint)f2bf(v.y * s) << 16);
        o.y = (uint)f2bf(v.z * s) | ((uint)f2bf(v.w * s) << 16);
    } else {
        o.x = 0u; o.y = 0u;
    }
    *(uint2*)(xh + e0) = o;
}

// one wave per dst row, 4 edges in flight, 16B/lane gather
__global__ void k_agg(const int* __restrict__ off, const int* __restrict__ eidx,
                      const ushort* __restrict__ xh, ushort* __restrict__ agg)
{
    int wid = threadIdx.x >> 6, lane = threadIdx.x & 63;
    int r = blockIdx.x * 4 + wid;
    if (r >= NPAD) return;
    int f = lane & 15;
    int g = lane >> 4;
    float a[8] = {0.f, 0.f, 0.f, 0.f, 0.f, 0.f, 0.f, 0.f};
    if (r < N_NODES) {
        int s = off[r], e = off[r + 1];
        for (int i = s + g; i < e; i += 4) {
            int sv = eidx[i];
            bfx8 v = *(const bfx8*)(xh + (size_t)sv * 128 + f * 8);
            #pragma unroll
            for (int k = 0; k < 8; ++k) a[k] += bf2f((ushort)v[k]);
        }
    }
    #pragma unroll
    for (int k = 0; k < 8; ++k) {
        a[k] += __shfl_xor(a[k], 16, 64);
        a[k] += __shfl_xor(a[k], 32, 64);
    }
    if (g == 0) {
        bfx8 o;
        #pragma unroll
        for (int k = 0; k < 8; ++k) o[k] = (short)f2bf(a[k]);
        *(bfx8*)(agg + (size_t)r * 128 + f * 8) = o;
    }
}

// transpose+convert weight [K,M] f32 -> [M,K] bf16
__global__ void k_wT(const float* __restrict__ W, int K, int M, ushort* __restrict__ Wt)
{
    int id = blockIdx.x * 256 + threadIdx.x;
    if (id < K * M) {
        int m = id / K, k = id - m * K;
        Wt[id] = f2bf(W[(size_t)k * M + m]);
    }
}

// ff2 weight prep with LN-gamma fold
__global__ void k_wT_ln(const float* __restrict__ W, const float* __restrict__ g,
                        const float* __restrict__ b, const float* __restrict__ b2,
                        ushort* __restrict__ Wt, float* __restrict__ u, float* __restrict__ t)
{
    int wid = threadIdx.x >> 6, lane = threadIdx.x & 63;
    int m = blockIdx.x * 4 + wid;
    if (m >= 128) return;
    float us = 0.f, ts = 0.f;
    for (int k = lane; k < 512; k += 64) {
        float w = W[(size_t)k * 128 + m];
        float gk = g[k], bk = b[k];
        Wt[(size_t)m * 512 + k] = f2bf(gk * w);
        us += gk * w; ts += bk * w;
    }
    us = wave_sum(us); ts = wave_sum(ts);
    if (lane == 0) { u[m] = us; t[m] = ts + b2[m]; }
}

// ---------------- GEMM: C = A @ Bt^T, bf16 MFMA ----------------
// EPI: 0 = rowv0[row]*acc + colv0[col]
//      1 = gelu(acc + colv0[col])
//      3 = rowv0[row]*acc + rowv1[row]*colv1[col] + colv0[col]   (folded LN)
// STATS: 0 none, 1 col sum/sumsq partials (per block, non-atomic), 2 row partials
template <int EPI, int STATS>
__global__ __launch_bounds__(256, 4) void k_gemm(
    const ushort* __restrict__ A, const ushort* __restrict__ Bt,
    ushort* __restrict__ C, int K, int M,
    const float* __restrict__ colv0, const float* __restrict__ rowv0,
    const float* __restrict__ rowv1, const float* __restrict__ colv1,
    float* __restrict__ pS, float* __restrict__ pQ, int grb0)
{
    __shared__ __align__(16) char smem[32768 + (STATS == 1 ? 1024 : 0)];
    char* AsB = smem;
    char* BsB = smem + 16384;

    const int nwg = gridDim.x;
    const int wgid = xcd_swz(blockIdx.x, nwg);
    const int nCB = M >> 7;
    const int cb = wgid % nCB;
    const int rb = wgid / nCB;
    const int tid = threadIdx.x;
    const int lane = tid & 63;
    const int wid = tid >> 6;
    const int m0 = (wid >> 1) * 64;
    const int n0 = (wid & 1) * 64;
    const int frl = lane & 15;
    const int kg = lane >> 4;

    float* statsf = (float*)(smem + 32768);
    if (STATS == 1 && tid < 128) { statsf[tid] = 0.f; statsf[128 + tid] = 0.f; }

    fx4 acc[4][4] = {};

    const ushort* Arow0 = A + (size_t)(rb * 128) * K;
    const ushort* Brow0 = Bt + (size_t)(cb * 128) * K;

    for (int kb = 0; kb < K; kb += 64) {
        #pragma unroll
        for (int c = 0; c < 4; ++c) {
            int b = c * 4096 + tid * 16;
            int row = b >> 7;
            int cibs = (b & 127) ^ ((row & 7) << 4);
            const char* ga = (const char*)(Arow0 + (size_t)row * K + kb) + cibs;
            const char* gb = (const char*)(Brow0 + (size_t)row * K + kb) + cibs;
            char* la = AsB + c * 4096 + (wid << 10);
            char* lb = BsB + c * 4096 + (wid << 10);
            __builtin_amdgcn_global_load_lds((const AS1 void*)ga, (AS3 void*)la, 16, 0, 0);
            __builtin_amdgcn_global_load_lds((const AS1 void*)gb, (AS3 void*)lb, 16, 0, 0);
        }
        __syncthreads();
        #pragma unroll
        for (int kk = 0; kk < 2; ++kk) {
            bfx8 av[4], bv[4];
            #pragma unroll
            for (int i = 0; i < 4; ++i) {
                int ar = m0 + i * 16 + frl;
                int ab = (ar * 128 + kk * 64 + kg * 16) ^ ((ar & 7) << 4);
                av[i] = *(const bfx8*)(AsB + ab);
                int br = n0 + i * 16 + frl;
                int bb = (br * 128 + kk * 64 + kg * 16) ^ ((br & 7) << 4);
                bv[i] = *(const bfx8*)(BsB + bb);
            }
            #pragma unroll
            for (int i = 0; i < 4; ++i)
                #pragma unroll
                for (int j = 0; j < 4; ++j)
                    acc[i][j] = __builtin_amdgcn_mfma_f32_16x16x32_bf16(av[i], bv[j], acc[i][j], 0, 0, 0);
        }
        __syncthreads();
    }

    // ---- epilogue: epi (+ col partials) -> LDS C-tile ----
    float sL[4] = {0.f, 0.f, 0.f, 0.f}, qL[4] = {0.f, 0.f, 0.f, 0.f};
    #pragma unroll
    for (int j = 0; j < 4; ++j) {
        int colL = n0 + j * 16 + frl;
        float c0 = colv0[cb * 128 + colL];
        float c1 = (EPI == 3) ? colv1[cb * 128 + colL] : 0.f;
        #pragma unroll
        for (int i = 0; i < 4; ++i) {
            int rbaseL = m0 + i * 16 + kg * 4;
            #pragma unroll
            for (int r = 0; r < 4; ++r) {
                float v = acc[i][j][r];
                int rowL = rbaseL + r;
                int grow = (grb0 + rb) * 128 + rowL;
                if (EPI == 0)      v = v * rowv0[grow] + c0;
                else if (EPI == 1) v = gelu_fast(v + c0);
                else if (EPI == 3) v = rowv0[grow] * v + rowv1[grow] * c1 + c0;
                if (STATS == 1) {
                    if (grow < N_NODES) { sL[j] += v; qL[j] += v * v; }
                }
                int boff = rowL * 256 + ((colL * 2) ^ ((rowL & 7) << 4));
                *(ushort*)(smem + boff) = f2bf(v);
            }
        }
    }
    if (STATS == 1) {
        #pragma unroll
        for (int j = 0; j < 4; ++j) {
            float s = sL[j], q = qL[j];
            s += __shfl_xor(s, 16, 64); s += __shfl_xor(s, 32, 64);
            q += __shfl_xor(q, 16, 64); q += __shfl_xor(q, 32, 64);
            if (kg == 0) {
                atomicAdd(&statsf[n0 + j * 16 + frl], s);
                atomicAdd(&statsf[128 + n0 + j * 16 + frl], q);
            }
        }
    }
    __syncthreads();
    // coalesced global write: 16 lanes x 16B = 256B per row
    {
        int r2 = tid >> 4;
        int s2 = tid & 15;
        #pragma unroll
        for (int pass = 0; pass < 8; ++pass) {
            int rowL = pass * 16 + r2;
            int boff = rowL * 256 + ((s2 * 16) ^ ((rowL & 7) << 4));
            bfx8 v = *(const bfx8*)(smem + boff);
            *(bfx8*)((char*)(C + (size_t)((grb0 + rb) * 128 + rowL - grb0 * 128) * M + cb * 128) + s2 * 16) = v;
        }
    }
    if (STATS == 1 && tid < 128) {
        size_t pidx = ((size_t)(grb0 + rb) * nCB + cb) * 128 + tid;
        pS[pidx] = statsf[tid];
        pQ[pidx] = statsf[128 + tid];
    }
    if (STATS == 2) {
        int rowL = tid >> 1, half = tid & 1;
        float s = 0.f, q = 0.f;
        #pragma unroll
        for (int ss = 0; ss < 8; ++ss) {
            int boff = rowL * 256 + (((half * 64 + ss * 8) * 2) ^ ((rowL & 7) << 4));
            bfx8 v = *(const bfx8*)(smem + boff);
            #pragma unroll
            for (int k2 = 0; k2 < 8; ++k2) {
                float f = bf2f((ushort)v[k2]);
                s += f; q += f * f;
            }
        }
        s += __shfl_xor(s, 1, 64);
        q += __shfl_xor(q, 1, 64);
        if (half == 0) {
            size_t pidx = (size_t)cb * NPAD + (size_t)(grb0 + rb) * 128 + rowL;
            pS[pidx] = s;
            pQ[pidx] = q;
        }
    }
}

// LN row stats: s_r = rsqrt(var+eps), c_r = -mean*s_r
__global__ void k_rowmerge(const float* __restrict__ pS, const float* __restrict__ pQ,
                           float* __restrict__ lnS, float* __restrict__ lnC)
{
    int r = blockIdx.x * 256 + threadIdx.x;
    if (r >= NPAD) return;
    float s = 0.f, q = 0.f;
    #pragma unroll
    for (int cb = 0; cb < 4; ++cb) {
        s += pS[(size_t)cb * NPAD + r];
        q += pQ[(size_t)cb * NPAD + r];
    }
    float mean = s * (1.f / 512.f);
    float var = fmaxf(q * (1.f / 512.f) - mean * mean, 0.f);
    float sr = rsqrtf(var + 1e-5f);
    lnS[r] = sr;
    lnC[r] = -mean * sr;
}

// merge col partials -> sums: ONE WAVE PER COLUMN (fix for round-6 regression)
__global__ void k_colmerge(const float* __restrict__ pS, const float* __restrict__ pQ,
                           float* __restrict__ oS, float* __restrict__ oQ, int M)
{
    int wid = threadIdx.x >> 6, lane = threadIdx.x & 63;
    int m = blockIdx.x * 4 + wid;
    if (m >= M) return;
    int nCB = M >> 7, cb = m >> 7, colL = m & 127;
    float s = 0.f, q = 0.f;
    for (int rb = lane; rb < NRB; rb += 64) {
        size_t idx = ((size_t)rb * nCB + cb) * 128 + colL;
        s += pS[idx]; q += pQ[idx];
    }
    s = wave_sum(s); q = wave_sum(q);
    if (lane == 0) { oS[m] = s; oQ[m] = q; }
}

// fold BN(prev-layer cols) into next weight
__global__ void k_fold(const float* __restrict__ W, const float* __restrict__ bw,
                       const float* __restrict__ g, const float* __restrict__ bb,
                       const float* __restrict__ sum, const float* __restrict__ sqs,
                       int K, int M, ushort* __restrict__ WtO, float* __restrict__ bO)
{
    int wid = threadIdx.x >> 6, lane = threadIdx.x & 63;
    int m = blockIdx.x * 4 + wid;
    if (m >= M) return;
    float acc = 0.f;
    for (int k = lane; k < K; k += 64) {
        float mean = sum[k] * (1.f / (float)N_NODES);
        float var = sqs[k] * (1.f / (float)N_NODES) - mean * mean;
        float s = g[k] * rsqrtf(var + 1e-5f);
        float t = bb[k] - mean * s;
        float w = W[(size_t)k * M + m];
        WtO[(size_t)m * K + k] = f2bf(w * s);
        acc += t * w;
    }
    acc = wave_sum(acc);
    if (lane == 0) bO[m] = bw[m] + acc;
}

// out[r] = dot(m3[r,:128], w4) + b4
__global__ void k_out(const ushort* __restrict__ m3, const ushort* __restrict__ w4,
                      const float* __restrict__ b4, float* __restrict__ out)
{
    int wid = threadIdx.x >> 6, lane = threadIdx.x & 63;
    int r = blockIdx.x * 4 + wid;
    if (r >= N_NODES) return;
    uint u = *(const uint*)(m3 + (size_t)r * 128 + lane * 2);
    uint w = *(const uint*)(w4 + lane * 2);
    float acc = bf2f((ushort)(u & 0xffffu)) * bf2f((ushort)(w & 0xffffu))
              + bf2f((ushort)(u >> 16)) * bf2f((ushort)(w >> 16));
    acc = wave_sum(acc);
    if (lane == 0) out[r] = acc + b4[0];
}

extern "C" void kernel_launch(void* const* d_in, const int* in_sizes, int n_in,
                              void* d_out, int out_size, void* d_ws, size_t ws_size,
                              hipStream_t stream)
{
    const float* x     = (const float*)d_in[0];
    const int*   src   = (const int*)d_in[1];
    const int*   dst   = (const int*)d_in[2];
    const float* gcn_w = (const float*)d_in[3];
    const float* gcn_b = (const float*)d_in[4];
    const float* ff_w1 = (const float*)d_in[5];
    const float* ff_b1 = (const float*)d_in[6];
    const float* ln_g  = (const float*)d_in[7];
    const float* ln_b  = (const float*)d_in[8];
    const float* ff_w2 = (const float*)d_in[9];
    const float* ff_b2 = (const float*)d_in[10];
    const float* fc1_w = (const float*)d_in[11];
    const float* fc1_b = (const float*)d_in[12];
    const float* bn1_g = (const float*)d_in[13];
    const float* bn1_b = (const float*)d_in[14];
    const float* fc2_w = (const float*)d_in[15];
    const float* fc2_b = (const float*)d_in[16];
    const float* bn2_g = (const float*)d_in[17];
    const float* bn2_b = (const float*)d_in[18];
    const float* fc3_w = (const float*)d_in[19];
    const float* fc3_b = (const float*)d_in[20];
    const float* bn3_g = (const float*)d_in[21];
    const float* bn3_b = (const float*)d_in[22];
    const float* fc4_w = (const float*)d_in[23];
    const float* fc4_b = (const float*)d_in[24];
    float* out = (float*)d_out;
    (void)in_sizes; (void)n_in; (void)out_size;

    char* base = (char*)d_ws;
    char* p = base;
    auto alloc = [&](size_t bytes) -> char* {
        char* r = p;
        p += (bytes + 255) & ~(size_t)255;
        return r;
    };
    int*    inc    = (int*)alloc((size_t)NPAD * 4);
    int*    cur    = (int*)alloc((size_t)NPAD * 4);
    int*    coff   = (int*)alloc(((size_t)NPAD + 1) * 4);
    int*    btot   = (int*)alloc(128 * 4);
    int*    eidx   = (int*)alloc((size_t)E_EDGES * 4);
    float*  oscale = (float*)alloc((size_t)NPAD * 4);
    float*  ininv  = (float*)alloc((size_t)NPAD * 4);
    float*  bns    = (float*)alloc(6 * 512 * 4);
    float*  b2p    = (float*)alloc(512 * 4);
    float*  b3p    = (float*)alloc(128 * 4);
    float*  b4p    = (float*)alloc(4);
    float*  lnS    = (float*)alloc((size_t)NPAD * 4);
    float*  lnC    = (float*)alloc((size_t)NPAD * 4);
    float*  lnU    = (float*)alloc(128 * 4);
    float*  lnT    = (float*)alloc(128 * 4);
    float*  pS     = (float*)alloc((size_t)4 * NPAD * 4);
    float*  pQ     = (float*)alloc((size_t)4 * NPAD * 4);
    ushort* gwT    = (ushort*)alloc(128 * 128 * 2);
    ushort* ff1T   = (ushort*)alloc(512 * 128 * 2);
    ushort* ff2T   = (ushort*)alloc(128 * 512 * 2);
    ushort* fc1T   = (ushort*)alloc(512 * 128 * 2);
    ushort* fc2T   = (ushort*)alloc(512 * 512 * 2);
    ushort* fc3T   = (ushort*)alloc(128 * 512 * 2);
    ushort* w4t    = (ushort*)alloc(128 * 2);
    ushort* buf1   = (ushort*)alloc((size_t)NPAD * 128 * 2);  // h -> h2 -> (fc2 tmp) -> m3
    ushort* bufC   = (ushort*)alloc((size_t)NPAD * 512 * 2);  // hist partials -> xh+agg -> f -> m1 [-> m2]

    size_t used = (size_t)(p - base);
    bool   sep  = (used + (size_t)NPAD * 512 * 2) <= ws_size;
    ushort* m2  = sep ? (ushort*)alloc((size_t)NPAD * 512 * 2) : bufC;

    uint* partO = (uint*)bufC;
    uint* partI = partO + (size_t)HNR * HP * (HRSZ / 2);
    ushort* xh  = bufC;
    ushort* agg = bufC + (size_t)NPAD * 128;

    float* bn1s = bns;
    float* bn1q = bns + 512;
    float* bn2s = bns + 1024;
    float* bn2q = bns + 1536;
    float* bn3s = bns + 2048;
    float* bn3q = bns + 2560;

    hipMemsetAsync(cur, 0, (size_t)NPAD * 4, stream);

    k_hist<<<HNR * HP, 256, 0, stream>>>(src, partO);
    k_hist<<<HNR * HP, 256, 0, stream>>>(dst, partI);
    k_degmerge<<<(NPAD + 255) / 256, 256, 0, stream>>>(partO, partI, inc, oscale, ininv);
    k_scan1<<<NBLK_SCAN, 1024, 0, stream>>>(inc, coff, btot);
    k_scan2<<<1, 128, 0, stream>>>(btot);
    k_scan3<<<(N_NODES + 255) / 256, 256, 0, stream>>>(coff, btot);
    k_fill<<<E_EDGES / 256, 256, 0, stream>>>(src, dst, coff, cur, eidx);
    k_xhat<<<(NPAD / 256) * 32, 256, 0, stream>>>(x, oscale, xh);
    k_agg<<<NPAD / 4, 256, 0, stream>>>(coff, eidx, xh, agg);

    k_wT<<<(128 * 128) / 256, 256, 0, stream>>>(gcn_w, 128, 128, gwT);
    k_wT<<<(128 * 512) / 256, 256, 0, stream>>>(ff_w1, 128, 512, ff1T);
    k_wT<<<(128 * 512) / 256, 256, 0, stream>>>(fc1_w, 128, 512, fc1T);
    k_wT_ln<<<32, 256, 0, stream>>>(ff_w2, ln_g, ln_b, ff_b2, ff2T, lnU, lnT);

    // GCN: h = (agg @ gcn_w) * ininv + gcn_b
    k_gemm<0, 0><<<NRB, 256, 0, stream>>>(agg, gwT, buf1, 128, 128,
                                          gcn_b, ininv, nullptr, nullptr, nullptr, nullptr, 0);
    // f = gelu(h @ ff_w1 + ff_b1) + row partials for LN
    k_gemm<1, 2><<<4 * NRB, 256, 0, stream>>>(buf1, ff1T, bufC, 128, 512,
                                              ff_b1, nullptr, nullptr, nullptr, pS, pQ, 0);
    k_rowmerge<<<(NPAD + 255) / 256, 256, 0, stream>>>(pS, pQ, lnS, lnC);
    // h2 = LN(f) @ ff_w2 + ff_b2 folded
    k_gemm<3, 0><<<NRB, 256, 0, stream>>>(bufC, ff2T, buf1, 512, 128,
                                          lnT, lnS, lnC, lnU, nullptr, nullptr, 0);
    // m1 = gelu(h2 @ fc1_w + fc1_b) + bn1 col partials
    k_gemm<1, 1><<<4 * NRB, 256, 0, stream>>>(buf1, fc1T, bufC, 128, 512,
                                              fc1_b, nullptr, nullptr, nullptr, pS, pQ, 0);
    k_colmerge<<<128, 256, 0, stream>>>(pS, pQ, bn1s, bn1q, 512);
    k_fold<<<512 / 4, 256, 0, stream>>>(fc2_w, fc2_b, bn1_g, bn1_b, bn1s, bn1q, 512, 512, fc2T, b2p);
    // m2 = gelu(bn1(m1) @ fc2_w + fc2_b) + bn2 col partials
    if (sep) {
        k_gemm<1, 1><<<4 * NRB, 256, 0, stream>>>(bufC, fc2T, m2, 512, 512,
                                                  b2p, nullptr, nullptr, nullptr, pS, pQ, 0);
    } else {
        const int cOff[6] = {0, 195, 390, 585, 780, 782};
        for (int c = 0; c < 5; ++c) {
            int rb0 = cOff[c], nrb = cOff[c + 1] - rb0;
            k_gemm<1, 1><<<nrb * 4, 256, 0, stream>>>(bufC + (size_t)rb0 * 128 * 512, fc2T,
                                                      buf1, 512, 512,
                                                      b2p, nullptr, nullptr, nullptr, pS, pQ, rb0);
            hipMemcpyAsync(bufC + (size_t)rb0 * 128 * 512, buf1,
                           (size_t)nrb * 128 * 512 * 2, hipMemcpyDeviceToDevice, stream);
        }
    }
    k_colmerge<<<128, 256, 0, stream>>>(pS, pQ, bn2s, bn2q, 512);
    k_fold<<<128 / 4, 256, 0, stream>>>(fc3_w, fc3_b, bn2_g, bn2_b, bn2s, bn2q, 512, 128, fc3T, b3p);
    // m3 = gelu(bn2(m2) @ fc3_w + fc3_b) + bn3 col partials
    k_gemm<1, 1><<<NRB, 256, 0, stream>>>(m2, fc3T, buf1, 512, 128,
                                          b3p, nullptr, nullptr, nullptr, pS, pQ, 0);
    k_colmerge<<<32, 256, 0, stream>>>(pS, pQ, bn3s, bn3q, 128);
    k_fold<<<1, 256, 0, stream>>>(fc4_w, fc4_b, bn3_g, bn3_b, bn3s, bn3q, 128, 1, w4t, b4p);
    k_out<<<N_NODES / 4, 256, 0, stream>>>(buf1, w4t, b4p, out);
}